// Round 15
// baseline (143.383 us; speedup 1.0000x reference)
//
#include <hip/hip_runtime.h>

static constexpr int kN   = 50000;    // nodes
static constexpr int kNR  = 100000;   // N*D rows
static constexpr int kE0  = 200000;   // original edges
static constexpr int kE2  = 400000;   // directed edges
static constexpr int kCAP = 32;       // adjacency capacity per node (Poisson(8): P(>=32)~7e-11)

typedef _Float16 f16;
typedef f16   f16x8 __attribute__((ext_vector_type(8)));
typedef f16   f16x4 __attribute__((ext_vector_type(4)));
typedef float f32x4 __attribute__((ext_vector_type(4)));

// ---------------------------------------------------------------------------
// k_wrh (fused init): zero cnt; convert W_right -> f16; block 0 builds
// Wsh8[8][128] f16: j = (p<<1)|h, p in {a0,a1,b0,b1}, h = K-half.
// ---------------------------------------------------------------------------
__global__ __launch_bounds__(256) void k_wrh(
    const float* __restrict__ Wr, const float* __restrict__ Wsh,
    f16* __restrict__ Wrh, f16* __restrict__ Wsh8, int* __restrict__ cnt)
{
    const int i = blockIdx.x * 256 + threadIdx.x;
    if (i < kN) cnt[i] = 0;
    if (i < 16384) Wrh[i] = (f16)Wr[i];
    if (blockIdx.x == 0) {
        #pragma unroll
        for (int q = 0; q < 4; ++q) {
            const int idx = q * 256 + threadIdx.x;  // j*128 + k
            const int j = idx >> 7, k = idx & 127;
            const int srcoff = ((j >> 2) ? 256 : 0) + (((j >> 1) & 1) ? 512 : 0) + ((j & 1) ? 128 : 0);
            Wsh8[idx] = (f16)Wsh[srcoff + k];
        }
    }
}

// ---------------------------------------------------------------------------
// k_node (fused): per block = 32 nodes (64 rows).
//  - stage RAW x rows as f16 into LDS Al (b128 writes)
//  - stage Wrh into LDS Bl ONCE per block (b128 copies) -> MFMA B-fragments
//    come from ds_read_b128, not global (kills the per-j L2 latency chain)
//  - pass 1 (ab): mfma(x_frag, Wsh8_frag); ab via shfl_xor(1) fold
//  - pass 2 (GEMM): tfr = cS*x[r] + cP*x[r^1]; mfma(Bl_frag, tfr) ->
//    lane holds 4 consecutive c of one node-row -> direct f16x4 store
// ---------------------------------------------------------------------------
__global__ __launch_bounds__(256) void k_node(
    const float* __restrict__ x, const float* __restrict__ Wl,
    const f16* __restrict__ Wrh, const f16* __restrict__ Wsh8,
    f16* __restrict__ xb, float* __restrict__ abf)
{
    __shared__ f16 Al[64][136];     // raw x rows (+8 pad)      17.4 KB
    __shared__ f16 Bl[128][136];    // W_right rows (+8 pad)    34.8 KB

    const int t   = threadIdx.x;
    const int blk = blockIdx.x;
    const float wl00 = Wl[0], wl01 = Wl[1], wl10 = Wl[2], wl11 = Wl[3];
    const int w = t >> 6, lane = t & 63;

    // stage Wrh -> Bl (vectorized, 8 iters of b128; coalesced global reads)
    #pragma unroll
    for (int i = 0; i < 8; ++i) {
        const int idx = i * 256 + t;         // f16x8-chunk index (2048 total)
        const int row = idx >> 4;            // 0..127
        const int c8  = (idx & 15) << 3;     // 0..120
        *(f16x8*)&Bl[row][c8] = *(const f16x8*)(Wrh + row * 128 + c8);
    }

    // stage raw x -> Al (b128 writes: 8 floats -> f16x8 per thread/iter)
    #pragma unroll
    for (int i = 0; i < 4; ++i) {
        const int f8   = i * 256 + t;        // f16x8-chunk index in 64x128 tile
        const int row  = f8 >> 4;            // 0..63
        const int c8   = (f8 & 15) << 3;     // 0..120
        const int grow = blk * 64 + row;
        float4 xa = make_float4(0.f, 0.f, 0.f, 0.f), xc = xa;
        if (grow < kNR) {
            xa = *(const float4*)(x + (size_t)grow * 128 + c8);
            xc = *(const float4*)(x + (size_t)grow * 128 + c8 + 4);
        }
        f16x8 tv;
        tv[0] = (f16)xa.x; tv[1] = (f16)xa.y; tv[2] = (f16)xa.z; tv[3] = (f16)xa.w;
        tv[4] = (f16)xc.x; tv[5] = (f16)xc.y; tv[6] = (f16)xc.z; tv[7] = (f16)xc.w;
        *(f16x8*)&Al[row][c8] = tv;
    }
    __syncthreads();

    const int lr = lane & 15, lk = lane >> 4;

    // load x fragments: own row r = 16w+lr and partner row r^1
    f16x8 xfr[4], xpr[4];
    #pragma unroll
    for (int kk = 0; kk < 4; ++kk) {
        xfr[kk] = *(const f16x8*)&Al[16 * w + lr][kk * 32 + lk * 8];
        xpr[kk] = *(const f16x8*)&Al[16 * w + (lr ^ 1)][kk * 32 + lk * 8];
    }

    // ---- pass 1: ab via MFMA (cols 8..15 zeroed) ----
    f32x4 cab = {0.f, 0.f, 0.f, 0.f};
    #pragma unroll
    for (int kk = 0; kk < 4; ++kk) {
        f16x8 bw = {};
        if (lr < 8) bw = *(const f16x8*)(Wsh8 + lr * 128 + kk * 32 + lk * 8);
        cab = __builtin_amdgcn_mfma_f32_16x16x32_f16(xfr[kk], bw, cab, 0, 0, 0);
    }
    #pragma unroll
    for (int tt = 0; tt < 2; ++tt) {
        const float hi_reg  = cab[2 * tt + 1];
        const float partner = __shfl_xor(hi_reg, 1);   // C[2n+1][lr^1]
        const float val     = cab[2 * tt] + partner;   // valid on even lr
        if (!(lr & 1) && lr < 8) {
            const int node = blk * 32 + 8 * w + 2 * lk + tt;
            if (node < kN) abf[node * 4 + (lr >> 1)] = val;
        }
    }

    // ---- pass 2: blend tmp fragments (packed f16) + main GEMM ----
    const int dp = lr & 1;
    const f16 cS = (f16)(dp ? wl11 : wl00);   // coeff on x[r]
    const f16 cP = (f16)(dp ? wl10 : wl01);   // coeff on x[r^1]
    const f16x8 cS8 = {cS, cS, cS, cS, cS, cS, cS, cS};
    const f16x8 cP8 = {cP, cP, cP, cP, cP, cP, cP, cP};
    f16x8 tfr[4];
    #pragma unroll
    for (int kk = 0; kk < 4; ++kk)
        tfr[kk] = cS8 * xfr[kk] + cP8 * xpr[kk];

    const int grow = blk * 64 + 16 * w + lr;   // node-row this lane outputs
    #pragma unroll
    for (int j = 0; j < 8; ++j) {
        f32x4 acc = {0.f, 0.f, 0.f, 0.f};
        #pragma unroll
        for (int kk = 0; kk < 4; ++kk) {
            const f16x8 wfr = *(const f16x8*)&Bl[j * 16 + lr][kk * 32 + lk * 8];
            acc = __builtin_amdgcn_mfma_f32_16x16x32_f16(wfr, tfr[kk], acc, 0, 0, 0);
        }
        f16x4 ov;
        ov[0] = (f16)(-acc[0]); ov[1] = (f16)(-acc[1]);
        ov[2] = (f16)(-acc[2]); ov[3] = (f16)(-acc[3]);
        if (grow < kNR)
            *(f16x4*)(xb + (size_t)grow * 128 + j * 16 + lk * 4) = ov;
    }
}

// ---------------------------------------------------------------------------
// k_edge1: per DIRECTED edge j in [0,2*E0): maps2[j] = tanh(a[row]+b[col]),
// adjacency append (1 atomic per directed edge; no diag atomics).
// ---------------------------------------------------------------------------
__global__ __launch_bounds__(256) void k_edge1(
    const int* __restrict__ src, const int* __restrict__ dst,
    const float4* __restrict__ ab, float2* __restrict__ maps2,
    int* __restrict__ cnt, int2* __restrict__ adj)
{
    const int j = blockIdx.x * 256 + threadIdx.x;
    if (j >= kE2) return;
    const bool fwd = j < kE0;
    const int o = fwd ? j : j - kE0;
    const int s = src[o], d = dst[o];
    const int row = fwd ? s : d;
    const int col = fwd ? d : s;
    const float4 ar = ab[row], ac = ab[col];
    const float m0 = tanhf(ar.x + ac.z);
    const float m1 = tanhf(ar.y + ac.w);
    maps2[j] = make_float2(m0, m1);
    const int p = atomicAdd(&cnt[row], 1);
    if (p < kCAP) adj[(size_t)row * kCAP + p] = make_int2(j, col);
}

// ---------------------------------------------------------------------------
// k_diag: 16 lanes per node. Parallel slot gathers (slots sl, sl+16),
// 4-step shfl reduce; sentinel-pads adjacency to multiple of 16.
// ---------------------------------------------------------------------------
__global__ __launch_bounds__(256) void k_diag(
    const int* __restrict__ cnt, int2* __restrict__ adj,
    const float2* __restrict__ maps2, float2* __restrict__ diag)
{
    const int node = blockIdx.x * 16 + (threadIdx.x >> 4);
    const int sl   = threadIdx.x & 15;
    if (node >= kN) return;
    int c = cnt[node];
    if (c > kCAP) c = kCAP;
    int2* al = adj + (size_t)node * kCAP;
    const int2 e0 = al[sl];
    const int2 e1 = al[sl + 16];
    float s0 = 0.f, s1 = 0.f;
    if (sl < c)      { const float2 m = maps2[e0.x]; s0 += m.x * m.x; s1 += m.y * m.y; }
    if (sl + 16 < c) { const float2 m = maps2[e1.x]; s0 += m.x * m.x; s1 += m.y * m.y; }
    const int cpad = (c + 15) & ~15;
    if (sl >= c && sl < cpad)           al[sl]      = make_int2(kE2, node);
    if (sl + 16 >= c && sl + 16 < cpad) al[sl + 16] = make_int2(kE2, node);
    #pragma unroll
    for (int o = 8; o > 0; o >>= 1) {
        s0 += __shfl_xor(s0, o);
        s1 += __shfl_xor(s1, o);
    }
    if (sl == 0) diag[node] = make_float2(s0, s1);
}

// ---------------------------------------------------------------------------
// k_off: per ORIGINAL edge j: off[j] = -m_fwd*m_bwd * rsqrt((ds+1)(dt+1))
// Thread kE0 also writes the sentinel zero entry off[kE0].
// ---------------------------------------------------------------------------
__global__ __launch_bounds__(256) void k_off(
    const int* __restrict__ src, const int* __restrict__ dst,
    const float2* __restrict__ maps2, const float2* __restrict__ diag,
    float2* __restrict__ off)
{
    const int j = blockIdx.x * 256 + threadIdx.x;
    if (j >= kE0) {
        if (j == kE0) off[kE0] = make_float2(0.f, 0.f);
        return;
    }
    const float2 ma = maps2[j];
    const float2 mb = maps2[j + kE0];
    const int s = src[j], d = dst[j];
    const float2 ds = diag[s], dt = diag[d];
    off[j] = make_float2(-ma.x * mb.x * rsqrtf((ds.x + 1.0f) * (dt.x + 1.0f)),
                         -ma.y * mb.y * rsqrtf((ds.y + 1.0f) * (dt.y + 1.0f)));
}

// ---------------------------------------------------------------------------
// k_gather: one wave per node; lane covers (d = lane>>5, h4 = (lane&31)*4)
// 16-wide mask-free MLP loop (adjacency padded to multiple of 16) —
// nearly all nodes (P(deg<=16)=0.98) complete in ONE latency trip.
// ALL NAMED SCALARS (no private arrays -> no LDS promotion).
// Neighbor accumulation in packed f16; f32 merge at the end.
// ---------------------------------------------------------------------------
__global__ __launch_bounds__(256) void k_gather(
    const f16* __restrict__ xb, const float* __restrict__ diag,
    const float2* __restrict__ off, const int* __restrict__ cnt,
    const int2* __restrict__ adj, float* __restrict__ y)
{
    const int node = blockIdx.x * 4 + (threadIdx.x >> 6);
    const int lane = threadIdx.x & 63;
    const int d    = lane >> 5;
    const int h4   = (lane & 31) << 2;
    const size_t rowoff = ((size_t)node * 2 + d) * 128 + h4;
    const f16x4 own = *(const f16x4*)(xb + rowoff);
    const float dv  = diag[node * 2 + d];
    const float dg  = dv / (dv + 1.0f);             // dis*diag*dis exactly
    f32x4 acc = {dg * (float)own[0], dg * (float)own[1],
                 dg * (float)own[2], dg * (float)own[3]};
    int c = cnt[node];
    if (c > kCAP) c = kCAP;
    const int2* al = adj + (size_t)node * kCAP;

    f16x4 acch = {(f16)0.f, (f16)0.f, (f16)0.f, (f16)0.f};
    for (int k = 0; k < c; k += 16) {
        const int4 ea = *(const int4*)(al + k);
        const int4 eb = *(const int4*)(al + k + 2);
        const int4 ec = *(const int4*)(al + k + 4);
        const int4 ed = *(const int4*)(al + k + 6);
        const int4 ee = *(const int4*)(al + k + 8);
        const int4 ef = *(const int4*)(al + k + 10);
        const int4 eg = *(const int4*)(al + k + 12);
        const int4 eh = *(const int4*)(al + k + 14);
        const int j0 = ea.x,  n0 = ea.y,  j1 = ea.z,  n1 = ea.w;
        const int j2 = eb.x,  n2 = eb.y,  j3 = eb.z,  n3 = eb.w;
        const int j4 = ec.x,  n4 = ec.y,  j5 = ec.z,  n5 = ec.w;
        const int j6 = ed.x,  n6 = ed.y,  j7 = ed.z,  n7 = ed.w;
        const int j8 = ee.x,  n8 = ee.y,  j9 = ee.z,  n9 = ee.w;
        const int jA = ef.x,  nA = ef.y,  jB = ef.z,  nB = ef.w;
        const int jC = eg.x,  nC = eg.y,  jD = eg.z,  nD = eg.w;
        const int jE = eh.x,  nE = eh.y,  jF = eh.z,  nF = eh.w;
        const float2 q0 = off[j0 - (j0 >= kE0 ? kE0 : 0)];
        const float2 q1 = off[j1 - (j1 >= kE0 ? kE0 : 0)];
        const float2 q2 = off[j2 - (j2 >= kE0 ? kE0 : 0)];
        const float2 q3 = off[j3 - (j3 >= kE0 ? kE0 : 0)];
        const float2 q4 = off[j4 - (j4 >= kE0 ? kE0 : 0)];
        const float2 q5 = off[j5 - (j5 >= kE0 ? kE0 : 0)];
        const float2 q6 = off[j6 - (j6 >= kE0 ? kE0 : 0)];
        const float2 q7 = off[j7 - (j7 >= kE0 ? kE0 : 0)];
        const float2 q8 = off[j8 - (j8 >= kE0 ? kE0 : 0)];
        const float2 q9 = off[j9 - (j9 >= kE0 ? kE0 : 0)];
        const float2 qA = off[jA - (jA >= kE0 ? kE0 : 0)];
        const float2 qB = off[jB - (jB >= kE0 ? kE0 : 0)];
        const float2 qC = off[jC - (jC >= kE0 ? kE0 : 0)];
        const float2 qD = off[jD - (jD >= kE0 ? kE0 : 0)];
        const float2 qE = off[jE - (jE >= kE0 ? kE0 : 0)];
        const float2 qF = off[jF - (jF >= kE0 ? kE0 : 0)];
        const f16x4 w0 = *(const f16x4*)(xb + ((size_t)n0 * 2 + d) * 128 + h4);
        const f16x4 w1 = *(const f16x4*)(xb + ((size_t)n1 * 2 + d) * 128 + h4);
        const f16x4 w2 = *(const f16x4*)(xb + ((size_t)n2 * 2 + d) * 128 + h4);
        const f16x4 w3 = *(const f16x4*)(xb + ((size_t)n3 * 2 + d) * 128 + h4);
        const f16x4 w4 = *(const f16x4*)(xb + ((size_t)n4 * 2 + d) * 128 + h4);
        const f16x4 w5 = *(const f16x4*)(xb + ((size_t)n5 * 2 + d) * 128 + h4);
        const f16x4 w6 = *(const f16x4*)(xb + ((size_t)n6 * 2 + d) * 128 + h4);
        const f16x4 w7 = *(const f16x4*)(xb + ((size_t)n7 * 2 + d) * 128 + h4);
        const f16x4 w8 = *(const f16x4*)(xb + ((size_t)n8 * 2 + d) * 128 + h4);
        const f16x4 w9 = *(const f16x4*)(xb + ((size_t)n9 * 2 + d) * 128 + h4);
        const f16x4 wA = *(const f16x4*)(xb + ((size_t)nA * 2 + d) * 128 + h4);
        const f16x4 wB = *(const f16x4*)(xb + ((size_t)nB * 2 + d) * 128 + h4);
        const f16x4 wC = *(const f16x4*)(xb + ((size_t)nC * 2 + d) * 128 + h4);
        const f16x4 wD = *(const f16x4*)(xb + ((size_t)nD * 2 + d) * 128 + h4);
        const f16x4 wE = *(const f16x4*)(xb + ((size_t)nE * 2 + d) * 128 + h4);
        const f16x4 wF = *(const f16x4*)(xb + ((size_t)nF * 2 + d) * 128 + h4);
        const f16 o0 = (f16)(d ? q0.y : q0.x);
        const f16 o1 = (f16)(d ? q1.y : q1.x);
        const f16 o2 = (f16)(d ? q2.y : q2.x);
        const f16 o3 = (f16)(d ? q3.y : q3.x);
        const f16 o4 = (f16)(d ? q4.y : q4.x);
        const f16 o5 = (f16)(d ? q5.y : q5.x);
        const f16 o6 = (f16)(d ? q6.y : q6.x);
        const f16 o7 = (f16)(d ? q7.y : q7.x);
        const f16 o8 = (f16)(d ? q8.y : q8.x);
        const f16 o9 = (f16)(d ? q9.y : q9.x);
        const f16 oA = (f16)(d ? qA.y : qA.x);
        const f16 oB = (f16)(d ? qB.y : qB.x);
        const f16 oC = (f16)(d ? qC.y : qC.x);
        const f16 oD = (f16)(d ? qD.y : qD.x);
        const f16 oE = (f16)(d ? qE.y : qE.x);
        const f16 oF = (f16)(d ? qF.y : qF.x);
        const f16x4 o40 = {o0, o0, o0, o0};  acch += o40 * w0;
        const f16x4 o41 = {o1, o1, o1, o1};  acch += o41 * w1;
        const f16x4 o42 = {o2, o2, o2, o2};  acch += o42 * w2;
        const f16x4 o43 = {o3, o3, o3, o3};  acch += o43 * w3;
        const f16x4 o44 = {o4, o4, o4, o4};  acch += o44 * w4;
        const f16x4 o45 = {o5, o5, o5, o5};  acch += o45 * w5;
        const f16x4 o46 = {o6, o6, o6, o6};  acch += o46 * w6;
        const f16x4 o47 = {o7, o7, o7, o7};  acch += o47 * w7;
        const f16x4 o48 = {o8, o8, o8, o8};  acch += o48 * w8;
        const f16x4 o49 = {o9, o9, o9, o9};  acch += o49 * w9;
        const f16x4 o4A = {oA, oA, oA, oA};  acch += o4A * wA;
        const f16x4 o4B = {oB, oB, oB, oB};  acch += o4B * wB;
        const f16x4 o4C = {oC, oC, oC, oC};  acch += o4C * wC;
        const f16x4 o4D = {oD, oD, oD, oD};  acch += o4D * wD;
        const f16x4 o4E = {oE, oE, oE, oE};  acch += o4E * wE;
        const f16x4 o4F = {oF, oF, oF, oF};  acch += o4F * wF;
    }
    acc[0] += (float)acch[0];
    acc[1] += (float)acch[1];
    acc[2] += (float)acch[2];
    acc[3] += (float)acch[3];
    __builtin_nontemporal_store(acc, (f32x4*)(y + rowoff));
}

// ---------------------------------------------------------------------------
extern "C" void kernel_launch(void* const* d_in, const int* in_sizes, int n_in,
                              void* d_out, int out_size, void* d_ws, size_t ws_size,
                              hipStream_t stream)
{
    const float* x   = (const float*)d_in[1];
    const int*   src = (const int*)d_in[2];
    const int*   dst = (const int*)d_in[3];
    const float* Wsh = (const float*)d_in[4];
    const float* Wl  = (const float*)d_in[5];
    const float* Wr  = (const float*)d_in[6];

    char* ws = (char*)d_ws;
    f16*    xb    = (f16*)   (ws + 0);           // 25,600,000 B
    float4* ab    = (float4*)(ws + 25600000);    //    800,000 B
    float2* maps2 = (float2*)(ws + 26400000);    //  3,200,000 B (2*E0 float2)
    float2* off   = (float2*)(ws + 29600000);    //  1,600,008 B (kE0+1 entries)
    float2* diag  = (float2*)(ws + 31200016);    //    400,000 B
    int*    cnt   = (int*)   (ws + 31600016);    //    200,000 B
    int2*   adj   = (int2*)  (ws + 31800016);    // 12,800,000 B (kCAP=32)
    f16*    Wrh   = (f16*)   (ws + 44600016);    //     32,768 B
    f16*    Wsh8  = (f16*)   (ws + 44632784);    //      2,048 B

    k_wrh   <<<196,   256, 0, stream>>>(Wr, Wsh, Wrh, Wsh8, cnt);
    k_node  <<<1563,  256, 0, stream>>>(x, Wl, Wrh, Wsh8, xb, (float*)ab);
    k_edge1 <<<1563,  256, 0, stream>>>(src, dst, ab, maps2, cnt, adj);
    k_diag  <<<3125,  256, 0, stream>>>(cnt, adj, maps2, diag);
    k_off   <<<783,   256, 0, stream>>>(src, dst, maps2, diag, off);
    k_gather<<<12500, 256, 0, stream>>>(xb, (const float*)diag, off, cnt, adj, (float*)d_out);
}

// Round 16
// 117.921 us; speedup vs baseline: 1.2159x; 1.2159x over previous
//
#include <hip/hip_runtime.h>

static constexpr int kN   = 50000;    // nodes
static constexpr int kNR  = 100000;   // N*D rows
static constexpr int kE0  = 200000;   // original edges
static constexpr int kE2  = 400000;   // directed edges
static constexpr int kCAP = 32;       // adjacency capacity per node (Poisson(8): P(>=32)~7e-11)

typedef _Float16 f16;
typedef f16   f16x8 __attribute__((ext_vector_type(8)));
typedef f16   f16x4 __attribute__((ext_vector_type(4)));
typedef float f32x4 __attribute__((ext_vector_type(4)));

// ---------------------------------------------------------------------------
// k_wrh (fused init): zero cnt; convert W_right -> f16; block 0 builds
// Wsh8[8][128] f16: j = (p<<1)|h, p in {a0,a1,b0,b1}, h = K-half.
// ---------------------------------------------------------------------------
__global__ __launch_bounds__(256) void k_wrh(
    const float* __restrict__ Wr, const float* __restrict__ Wsh,
    f16* __restrict__ Wrh, f16* __restrict__ Wsh8, int* __restrict__ cnt)
{
    const int i = blockIdx.x * 256 + threadIdx.x;
    if (i < kN) cnt[i] = 0;
    if (i < 16384) Wrh[i] = (f16)Wr[i];
    if (blockIdx.x == 0) {
        #pragma unroll
        for (int q = 0; q < 4; ++q) {
            const int idx = q * 256 + threadIdx.x;  // j*128 + k
            const int j = idx >> 7, k = idx & 127;
            const int srcoff = ((j >> 2) ? 256 : 0) + (((j >> 1) & 1) ? 512 : 0) + ((j & 1) ? 128 : 0);
            Wsh8[idx] = (f16)Wsh[srcoff + k];
        }
    }
}

// ---------------------------------------------------------------------------
// k_node (fused): per block = 32 nodes (64 rows).
//  - stage RAW x rows as f16 into LDS Al (b128 writes)
//  - stage Wrh into LDS Bl ONCE per block (b128 copies) -> MFMA B-fragments
//    come from ds_read_b128, not global (kills the per-j L2 latency chain;
//    r15 counters: non-gather time 84 -> 66 us with this staging)
//  - pass 1 (ab): mfma(x_frag, Wsh8_frag); ab via shfl_xor(1) fold
//  - pass 2 (GEMM): tfr = cS*x[r] + cP*x[r^1]; mfma(Bl_frag, tfr) ->
//    lane holds 4 consecutive c of one node-row -> direct f16x4 store
// ---------------------------------------------------------------------------
__global__ __launch_bounds__(256) void k_node(
    const float* __restrict__ x, const float* __restrict__ Wl,
    const f16* __restrict__ Wrh, const f16* __restrict__ Wsh8,
    f16* __restrict__ xb, float* __restrict__ abf)
{
    __shared__ f16 Al[64][136];     // raw x rows (+8 pad)      17.4 KB
    __shared__ f16 Bl[128][136];    // W_right rows (+8 pad)    34.8 KB

    const int t   = threadIdx.x;
    const int blk = blockIdx.x;
    const float wl00 = Wl[0], wl01 = Wl[1], wl10 = Wl[2], wl11 = Wl[3];
    const int w = t >> 6, lane = t & 63;

    // stage Wrh -> Bl (vectorized, 8 iters of b128; coalesced global reads)
    #pragma unroll
    for (int i = 0; i < 8; ++i) {
        const int idx = i * 256 + t;         // f16x8-chunk index (2048 total)
        const int row = idx >> 4;            // 0..127
        const int c8  = (idx & 15) << 3;     // 0..120
        *(f16x8*)&Bl[row][c8] = *(const f16x8*)(Wrh + row * 128 + c8);
    }

    // stage raw x -> Al (b128 writes: 8 floats -> f16x8 per thread/iter)
    #pragma unroll
    for (int i = 0; i < 4; ++i) {
        const int f8   = i * 256 + t;        // f16x8-chunk index in 64x128 tile
        const int row  = f8 >> 4;            // 0..63
        const int c8   = (f8 & 15) << 3;     // 0..120
        const int grow = blk * 64 + row;
        float4 xa = make_float4(0.f, 0.f, 0.f, 0.f), xc = xa;
        if (grow < kNR) {
            xa = *(const float4*)(x + (size_t)grow * 128 + c8);
            xc = *(const float4*)(x + (size_t)grow * 128 + c8 + 4);
        }
        f16x8 tv;
        tv[0] = (f16)xa.x; tv[1] = (f16)xa.y; tv[2] = (f16)xa.z; tv[3] = (f16)xa.w;
        tv[4] = (f16)xc.x; tv[5] = (f16)xc.y; tv[6] = (f16)xc.z; tv[7] = (f16)xc.w;
        *(f16x8*)&Al[row][c8] = tv;
    }
    __syncthreads();

    const int lr = lane & 15, lk = lane >> 4;

    // load x fragments: own row r = 16w+lr and partner row r^1
    f16x8 xfr[4], xpr[4];
    #pragma unroll
    for (int kk = 0; kk < 4; ++kk) {
        xfr[kk] = *(const f16x8*)&Al[16 * w + lr][kk * 32 + lk * 8];
        xpr[kk] = *(const f16x8*)&Al[16 * w + (lr ^ 1)][kk * 32 + lk * 8];
    }

    // ---- pass 1: ab via MFMA (cols 8..15 zeroed) ----
    f32x4 cab = {0.f, 0.f, 0.f, 0.f};
    #pragma unroll
    for (int kk = 0; kk < 4; ++kk) {
        f16x8 bw = {};
        if (lr < 8) bw = *(const f16x8*)(Wsh8 + lr * 128 + kk * 32 + lk * 8);
        cab = __builtin_amdgcn_mfma_f32_16x16x32_f16(xfr[kk], bw, cab, 0, 0, 0);
    }
    #pragma unroll
    for (int tt = 0; tt < 2; ++tt) {
        const float hi_reg  = cab[2 * tt + 1];
        const float partner = __shfl_xor(hi_reg, 1);   // C[2n+1][lr^1]
        const float val     = cab[2 * tt] + partner;   // valid on even lr
        if (!(lr & 1) && lr < 8) {
            const int node = blk * 32 + 8 * w + 2 * lk + tt;
            if (node < kN) abf[node * 4 + (lr >> 1)] = val;
        }
    }

    // ---- pass 2: blend tmp fragments (packed f16) + main GEMM ----
    const int dp = lr & 1;
    const f16 cS = (f16)(dp ? wl11 : wl00);   // coeff on x[r]
    const f16 cP = (f16)(dp ? wl10 : wl01);   // coeff on x[r^1]
    const f16x8 cS8 = {cS, cS, cS, cS, cS, cS, cS, cS};
    const f16x8 cP8 = {cP, cP, cP, cP, cP, cP, cP, cP};
    f16x8 tfr[4];
    #pragma unroll
    for (int kk = 0; kk < 4; ++kk)
        tfr[kk] = cS8 * xfr[kk] + cP8 * xpr[kk];

    const int grow = blk * 64 + 16 * w + lr;   // node-row this lane outputs
    #pragma unroll
    for (int j = 0; j < 8; ++j) {
        f32x4 acc = {0.f, 0.f, 0.f, 0.f};
        #pragma unroll
        for (int kk = 0; kk < 4; ++kk) {
            const f16x8 wfr = *(const f16x8*)&Bl[j * 16 + lr][kk * 32 + lk * 8];
            acc = __builtin_amdgcn_mfma_f32_16x16x32_f16(wfr, tfr[kk], acc, 0, 0, 0);
        }
        f16x4 ov;
        ov[0] = (f16)(-acc[0]); ov[1] = (f16)(-acc[1]);
        ov[2] = (f16)(-acc[2]); ov[3] = (f16)(-acc[3]);
        if (grow < kNR)
            *(f16x4*)(xb + (size_t)grow * 128 + j * 16 + lk * 4) = ov;
    }
}

// ---------------------------------------------------------------------------
// k_edge1: per DIRECTED edge j in [0,2*E0): maps2[j] = tanh(a[row]+b[col]),
// adjacency append (1 atomic per directed edge; no diag atomics).
// ---------------------------------------------------------------------------
__global__ __launch_bounds__(256) void k_edge1(
    const int* __restrict__ src, const int* __restrict__ dst,
    const float4* __restrict__ ab, float2* __restrict__ maps2,
    int* __restrict__ cnt, int2* __restrict__ adj)
{
    const int j = blockIdx.x * 256 + threadIdx.x;
    if (j >= kE2) return;
    const bool fwd = j < kE0;
    const int o = fwd ? j : j - kE0;
    const int s = src[o], d = dst[o];
    const int row = fwd ? s : d;
    const int col = fwd ? d : s;
    const float4 ar = ab[row], ac = ab[col];
    const float m0 = tanhf(ar.x + ac.z);
    const float m1 = tanhf(ar.y + ac.w);
    maps2[j] = make_float2(m0, m1);
    const int p = atomicAdd(&cnt[row], 1);
    if (p < kCAP) adj[(size_t)row * kCAP + p] = make_int2(j, col);
}

// ---------------------------------------------------------------------------
// k_diag: 16 lanes per node. Parallel slot gathers (slots sl, sl+16),
// 4-step shfl reduce; sentinel-pads adjacency to multiple of 8.
// ---------------------------------------------------------------------------
__global__ __launch_bounds__(256) void k_diag(
    const int* __restrict__ cnt, int2* __restrict__ adj,
    const float2* __restrict__ maps2, float2* __restrict__ diag)
{
    const int node = blockIdx.x * 16 + (threadIdx.x >> 4);
    const int sl   = threadIdx.x & 15;
    if (node >= kN) return;
    int c = cnt[node];
    if (c > kCAP) c = kCAP;
    int2* al = adj + (size_t)node * kCAP;
    const int2 e0 = al[sl];
    const int2 e1 = al[sl + 16];
    float s0 = 0.f, s1 = 0.f;
    if (sl < c)      { const float2 m = maps2[e0.x]; s0 += m.x * m.x; s1 += m.y * m.y; }
    if (sl + 16 < c) { const float2 m = maps2[e1.x]; s0 += m.x * m.x; s1 += m.y * m.y; }
    const int cpad = (c + 7) & ~7;
    if (sl >= c && sl < cpad)           al[sl]      = make_int2(kE2, node);
    if (sl + 16 >= c && sl + 16 < cpad) al[sl + 16] = make_int2(kE2, node);
    #pragma unroll
    for (int o = 8; o > 0; o >>= 1) {
        s0 += __shfl_xor(s0, o);
        s1 += __shfl_xor(s1, o);
    }
    if (sl == 0) diag[node] = make_float2(s0, s1);
}

// ---------------------------------------------------------------------------
// k_off: per ORIGINAL edge j: off[j] = -m_fwd*m_bwd * rsqrt((ds+1)(dt+1))
// Thread kE0 also writes the sentinel zero entry off[kE0].
// ---------------------------------------------------------------------------
__global__ __launch_bounds__(256) void k_off(
    const int* __restrict__ src, const int* __restrict__ dst,
    const float2* __restrict__ maps2, const float2* __restrict__ diag,
    float2* __restrict__ off)
{
    const int j = blockIdx.x * 256 + threadIdx.x;
    if (j >= kE0) {
        if (j == kE0) off[kE0] = make_float2(0.f, 0.f);
        return;
    }
    const float2 ma = maps2[j];
    const float2 mb = maps2[j + kE0];
    const int s = src[j], d = dst[j];
    const float2 ds = diag[s], dt = diag[d];
    off[j] = make_float2(-ma.x * mb.x * rsqrtf((ds.x + 1.0f) * (dt.x + 1.0f)),
                         -ma.y * mb.y * rsqrtf((ds.y + 1.0f) * (dt.y + 1.0f)));
}

// ---------------------------------------------------------------------------
// k_gather: one wave per node; lane covers (d = lane>>5, h4 = (lane&31)*4)
// 8-wide mask-free MLP loop (pad to mult of 8 — r15 showed time scales with
// padded slot count, so 8 is the sweet spot: E[slots]=11.4 vs 16.6 at 16).
// ALL NAMED SCALARS (no private arrays -> no LDS promotion).
// Neighbor accumulation in packed f16; f32 merge at the end.
// ---------------------------------------------------------------------------
__global__ __launch_bounds__(256) void k_gather(
    const f16* __restrict__ xb, const float* __restrict__ diag,
    const float2* __restrict__ off, const int* __restrict__ cnt,
    const int2* __restrict__ adj, float* __restrict__ y)
{
    const int node = blockIdx.x * 4 + (threadIdx.x >> 6);
    const int lane = threadIdx.x & 63;
    const int d    = lane >> 5;
    const int h4   = (lane & 31) << 2;
    const size_t rowoff = ((size_t)node * 2 + d) * 128 + h4;
    const f16x4 own = *(const f16x4*)(xb + rowoff);
    const float dv  = diag[node * 2 + d];
    const float dg  = dv / (dv + 1.0f);             // dis*diag*dis exactly
    f32x4 acc = {dg * (float)own[0], dg * (float)own[1],
                 dg * (float)own[2], dg * (float)own[3]};
    int c = cnt[node];
    if (c > kCAP) c = kCAP;
    const int2* al = adj + (size_t)node * kCAP;

    f16x4 acch = {(f16)0.f, (f16)0.f, (f16)0.f, (f16)0.f};
    for (int k = 0; k < c; k += 8) {
        const int4 ea = *(const int4*)(al + k);
        const int4 eb = *(const int4*)(al + k + 2);
        const int4 ec = *(const int4*)(al + k + 4);
        const int4 ed = *(const int4*)(al + k + 6);
        const int j0 = ea.x, n0 = ea.y, j1 = ea.z, n1 = ea.w;
        const int j2 = eb.x, n2 = eb.y, j3 = eb.z, n3 = eb.w;
        const int j4 = ec.x, n4 = ec.y, j5 = ec.z, n5 = ec.w;
        const int j6 = ed.x, n6 = ed.y, j7 = ed.z, n7 = ed.w;
        const float2 q0 = off[j0 - (j0 >= kE0 ? kE0 : 0)];
        const float2 q1 = off[j1 - (j1 >= kE0 ? kE0 : 0)];
        const float2 q2 = off[j2 - (j2 >= kE0 ? kE0 : 0)];
        const float2 q3 = off[j3 - (j3 >= kE0 ? kE0 : 0)];
        const float2 q4 = off[j4 - (j4 >= kE0 ? kE0 : 0)];
        const float2 q5 = off[j5 - (j5 >= kE0 ? kE0 : 0)];
        const float2 q6 = off[j6 - (j6 >= kE0 ? kE0 : 0)];
        const float2 q7 = off[j7 - (j7 >= kE0 ? kE0 : 0)];
        const f16x4 w0 = *(const f16x4*)(xb + ((size_t)n0 * 2 + d) * 128 + h4);
        const f16x4 w1 = *(const f16x4*)(xb + ((size_t)n1 * 2 + d) * 128 + h4);
        const f16x4 w2 = *(const f16x4*)(xb + ((size_t)n2 * 2 + d) * 128 + h4);
        const f16x4 w3 = *(const f16x4*)(xb + ((size_t)n3 * 2 + d) * 128 + h4);
        const f16x4 w4 = *(const f16x4*)(xb + ((size_t)n4 * 2 + d) * 128 + h4);
        const f16x4 w5 = *(const f16x4*)(xb + ((size_t)n5 * 2 + d) * 128 + h4);
        const f16x4 w6 = *(const f16x4*)(xb + ((size_t)n6 * 2 + d) * 128 + h4);
        const f16x4 w7 = *(const f16x4*)(xb + ((size_t)n7 * 2 + d) * 128 + h4);
        const f16 o0 = (f16)(d ? q0.y : q0.x);
        const f16 o1 = (f16)(d ? q1.y : q1.x);
        const f16 o2 = (f16)(d ? q2.y : q2.x);
        const f16 o3 = (f16)(d ? q3.y : q3.x);
        const f16 o4 = (f16)(d ? q4.y : q4.x);
        const f16 o5 = (f16)(d ? q5.y : q5.x);
        const f16 o6 = (f16)(d ? q6.y : q6.x);
        const f16 o7 = (f16)(d ? q7.y : q7.x);
        const f16x4 o40 = {o0, o0, o0, o0};
        const f16x4 o41 = {o1, o1, o1, o1};
        const f16x4 o42 = {o2, o2, o2, o2};
        const f16x4 o43 = {o3, o3, o3, o3};
        const f16x4 o44 = {o4, o4, o4, o4};
        const f16x4 o45 = {o5, o5, o5, o5};
        const f16x4 o46 = {o6, o6, o6, o6};
        const f16x4 o47 = {o7, o7, o7, o7};
        acch += o40 * w0;   // v_pk_fma_f16 pairs
        acch += o41 * w1;
        acch += o42 * w2;
        acch += o43 * w3;
        acch += o44 * w4;
        acch += o45 * w5;
        acch += o46 * w6;
        acch += o47 * w7;
    }
    acc[0] += (float)acch[0];
    acc[1] += (float)acch[1];
    acc[2] += (float)acch[2];
    acc[3] += (float)acch[3];
    __builtin_nontemporal_store(acc, (f32x4*)(y + rowoff));
}

// ---------------------------------------------------------------------------
extern "C" void kernel_launch(void* const* d_in, const int* in_sizes, int n_in,
                              void* d_out, int out_size, void* d_ws, size_t ws_size,
                              hipStream_t stream)
{
    const float* x   = (const float*)d_in[1];
    const int*   src = (const int*)d_in[2];
    const int*   dst = (const int*)d_in[3];
    const float* Wsh = (const float*)d_in[4];
    const float* Wl  = (const float*)d_in[5];
    const float* Wr  = (const float*)d_in[6];

    char* ws = (char*)d_ws;
    f16*    xb    = (f16*)   (ws + 0);           // 25,600,000 B
    float4* ab    = (float4*)(ws + 25600000);    //    800,000 B
    float2* maps2 = (float2*)(ws + 26400000);    //  3,200,000 B (2*E0 float2)
    float2* off   = (float2*)(ws + 29600000);    //  1,600,008 B (kE0+1 entries)
    float2* diag  = (float2*)(ws + 31200016);    //    400,000 B
    int*    cnt   = (int*)   (ws + 31600016);    //    200,000 B
    int2*   adj   = (int2*)  (ws + 31800016);    // 12,800,000 B (kCAP=32)
    f16*    Wrh   = (f16*)   (ws + 44600016);    //     32,768 B
    f16*    Wsh8  = (f16*)   (ws + 44632784);    //      2,048 B

    k_wrh   <<<196,   256, 0, stream>>>(Wr, Wsh, Wrh, Wsh8, cnt);
    k_node  <<<1563,  256, 0, stream>>>(x, Wl, Wrh, Wsh8, xb, (float*)ab);
    k_edge1 <<<1563,  256, 0, stream>>>(src, dst, ab, maps2, cnt, adj);
    k_diag  <<<3125,  256, 0, stream>>>(cnt, adj, maps2, diag);
    k_off   <<<783,   256, 0, stream>>>(src, dst, maps2, diag, off);
    k_gather<<<12500, 256, 0, stream>>>(xb, (const float*)diag, off, cnt, adj, (float*)d_out);
}

// Round 17
// 115.085 us; speedup vs baseline: 1.2459x; 1.0246x over previous
//
#include <hip/hip_runtime.h>

static constexpr int kN   = 50000;    // nodes
static constexpr int kNR  = 100000;   // N*D rows
static constexpr int kE0  = 200000;   // original edges
static constexpr int kE2  = 400000;   // directed edges
static constexpr int kCAP = 32;       // adjacency capacity per node (Poisson(8): P(>=32)~7e-11)

typedef _Float16 f16;
typedef f16   f16x8 __attribute__((ext_vector_type(8)));
typedef f16   f16x4 __attribute__((ext_vector_type(4)));
typedef float f32x4 __attribute__((ext_vector_type(4)));

// ---------------------------------------------------------------------------
// k_node (fused): per block = 32 nodes (64 rows). First dispatch:
//  - zeroes cnt (gid < kN)
//  - stages W_right f32 -> LDS Bl f16 directly (64KB/block, L2-hot)
//  - stages RAW x rows as f16 into LDS Al (b128 writes)
//  - pass 1 (ab): mfma(x_frag, Wsh-f32-direct frag); ab via shfl_xor(1) fold
//  - pass 2 (GEMM): tfr = cS*x[r] + cP*x[r^1]; mfma(Bl_frag, tfr) ->
//    lane holds 4 consecutive c of one node-row -> direct f16x4 store
// ---------------------------------------------------------------------------
__global__ __launch_bounds__(256) void k_node(
    const float* __restrict__ x, const float* __restrict__ Wsh,
    const float* __restrict__ Wl, const float* __restrict__ Wr,
    f16* __restrict__ xb, float* __restrict__ abf, int* __restrict__ cnt)
{
    __shared__ f16 Al[64][136];     // raw x rows (+8 pad)      17.4 KB
    __shared__ f16 Bl[128][136];    // W_right rows (+8 pad)    34.8 KB

    const int t   = threadIdx.x;
    const int blk = blockIdx.x;
    const float wl00 = Wl[0], wl01 = Wl[1], wl10 = Wl[2], wl11 = Wl[3];
    const int w = t >> 6, lane = t & 63;

    // zero cnt (grid covers 400K threads >= kN)
    const int gid = blk * 256 + t;
    if (gid < kN) cnt[gid] = 0;

    // stage Wr f32 -> Bl f16 (2048 f16x8-chunks; 8 per thread; coalesced)
    #pragma unroll
    for (int i = 0; i < 8; ++i) {
        const int idx = i * 256 + t;
        const int row = idx >> 4;            // 0..127
        const int c8  = (idx & 15) << 3;     // 0..120
        const float4 a = *(const float4*)(Wr + row * 128 + c8);
        const float4 b = *(const float4*)(Wr + row * 128 + c8 + 4);
        f16x8 tv;
        tv[0] = (f16)a.x; tv[1] = (f16)a.y; tv[2] = (f16)a.z; tv[3] = (f16)a.w;
        tv[4] = (f16)b.x; tv[5] = (f16)b.y; tv[6] = (f16)b.z; tv[7] = (f16)b.w;
        *(f16x8*)&Bl[row][c8] = tv;
    }

    // stage raw x -> Al (b128 writes: 8 floats -> f16x8 per thread/iter)
    #pragma unroll
    for (int i = 0; i < 4; ++i) {
        const int f8   = i * 256 + t;        // f16x8-chunk index in 64x128 tile
        const int row  = f8 >> 4;            // 0..63
        const int c8   = (f8 & 15) << 3;     // 0..120
        const int grow = blk * 64 + row;
        float4 xa = make_float4(0.f, 0.f, 0.f, 0.f), xc = xa;
        if (grow < kNR) {
            xa = *(const float4*)(x + (size_t)grow * 128 + c8);
            xc = *(const float4*)(x + (size_t)grow * 128 + c8 + 4);
        }
        f16x8 tv;
        tv[0] = (f16)xa.x; tv[1] = (f16)xa.y; tv[2] = (f16)xa.z; tv[3] = (f16)xa.w;
        tv[4] = (f16)xc.x; tv[5] = (f16)xc.y; tv[6] = (f16)xc.z; tv[7] = (f16)xc.w;
        *(f16x8*)&Al[row][c8] = tv;
    }
    __syncthreads();

    const int lr = lane & 15, lk = lane >> 4;

    // load x fragments: own row r = 16w+lr and partner row r^1
    f16x8 xfr[4], xpr[4];
    #pragma unroll
    for (int kk = 0; kk < 4; ++kk) {
        xfr[kk] = *(const f16x8*)&Al[16 * w + lr][kk * 32 + lk * 8];
        xpr[kk] = *(const f16x8*)&Al[16 * w + (lr ^ 1)][kk * 32 + lk * 8];
    }

    // ---- pass 1: ab via MFMA; B-fragments straight from Wsh f32 (L2-hot) ----
    // row j=lr of the 8-vector table: p=(lr>>1) in {a0,a1,b0,b1}, h=lr&1
    f32x4 cab = {0.f, 0.f, 0.f, 0.f};
    const int srcoff = ((lr >> 2) ? 256 : 0) + (((lr >> 1) & 1) ? 512 : 0) + ((lr & 1) ? 128 : 0);
    #pragma unroll
    for (int kk = 0; kk < 4; ++kk) {
        f16x8 bw = {};
        if (lr < 8) {
            const float4 a = *(const float4*)(Wsh + srcoff + kk * 32 + lk * 8);
            const float4 b = *(const float4*)(Wsh + srcoff + kk * 32 + lk * 8 + 4);
            bw[0] = (f16)a.x; bw[1] = (f16)a.y; bw[2] = (f16)a.z; bw[3] = (f16)a.w;
            bw[4] = (f16)b.x; bw[5] = (f16)b.y; bw[6] = (f16)b.z; bw[7] = (f16)b.w;
        }
        cab = __builtin_amdgcn_mfma_f32_16x16x32_f16(xfr[kk], bw, cab, 0, 0, 0);
    }
    #pragma unroll
    for (int tt = 0; tt < 2; ++tt) {
        const float hi_reg  = cab[2 * tt + 1];
        const float partner = __shfl_xor(hi_reg, 1);   // C[2n+1][lr^1]
        const float val     = cab[2 * tt] + partner;   // valid on even lr
        if (!(lr & 1) && lr < 8) {
            const int node = blk * 32 + 8 * w + 2 * lk + tt;
            if (node < kN) abf[node * 4 + (lr >> 1)] = val;
        }
    }

    // ---- pass 2: blend tmp fragments (packed f16) + main GEMM ----
    const int dp = lr & 1;
    const f16 cS = (f16)(dp ? wl11 : wl00);   // coeff on x[r]
    const f16 cP = (f16)(dp ? wl10 : wl01);   // coeff on x[r^1]
    const f16x8 cS8 = {cS, cS, cS, cS, cS, cS, cS, cS};
    const f16x8 cP8 = {cP, cP, cP, cP, cP, cP, cP, cP};
    f16x8 tfr[4];
    #pragma unroll
    for (int kk = 0; kk < 4; ++kk)
        tfr[kk] = cS8 * xfr[kk] + cP8 * xpr[kk];

    const int grow = blk * 64 + 16 * w + lr;   // node-row this lane outputs
    #pragma unroll
    for (int j = 0; j < 8; ++j) {
        f32x4 acc = {0.f, 0.f, 0.f, 0.f};
        #pragma unroll
        for (int kk = 0; kk < 4; ++kk) {
            const f16x8 wfr = *(const f16x8*)&Bl[j * 16 + lr][kk * 32 + lk * 8];
            acc = __builtin_amdgcn_mfma_f32_16x16x32_f16(wfr, tfr[kk], acc, 0, 0, 0);
        }
        f16x4 ov;
        ov[0] = (f16)(-acc[0]); ov[1] = (f16)(-acc[1]);
        ov[2] = (f16)(-acc[2]); ov[3] = (f16)(-acc[3]);
        if (grow < kNR)
            *(f16x4*)(xb + (size_t)grow * 128 + j * 16 + lk * 4) = ov;
    }
}

// ---------------------------------------------------------------------------
// k_edge1: per ORIGINAL edge j (200K threads): both directions share the
// same two ab float4s (halves random gathers vs per-directed-edge).
// maps2[j] = fwd, maps2[j+kE0] = bwd; 2 cnt atomics + 2 adj appends.
// ---------------------------------------------------------------------------
__global__ __launch_bounds__(256) void k_edge1(
    const int* __restrict__ src, const int* __restrict__ dst,
    const float4* __restrict__ ab, float2* __restrict__ maps2,
    int* __restrict__ cnt, int2* __restrict__ adj)
{
    const int j = blockIdx.x * 256 + threadIdx.x;
    if (j >= kE0) return;
    const int s = src[j], d = dst[j];
    const float4 as_ = ab[s], ad = ab[d];
    const float f0 = tanhf(as_.x + ad.z);
    const float f1 = tanhf(as_.y + ad.w);
    const float b0 = tanhf(ad.x + as_.z);
    const float b1 = tanhf(ad.y + as_.w);
    maps2[j]       = make_float2(f0, f1);
    maps2[j + kE0] = make_float2(b0, b1);
    const int p = atomicAdd(&cnt[s], 1);
    if (p < kCAP) adj[(size_t)s * kCAP + p] = make_int2(j, d);
    const int q = atomicAdd(&cnt[d], 1);
    if (q < kCAP) adj[(size_t)d * kCAP + q] = make_int2(j + kE0, s);
}

// ---------------------------------------------------------------------------
// k_diag: 16 lanes per node. Parallel slot gathers (slots sl, sl+16),
// 4-step shfl reduce; sentinel-pads adjacency to multiple of 8.
// ---------------------------------------------------------------------------
__global__ __launch_bounds__(256) void k_diag(
    const int* __restrict__ cnt, int2* __restrict__ adj,
    const float2* __restrict__ maps2, float2* __restrict__ diag)
{
    const int node = blockIdx.x * 16 + (threadIdx.x >> 4);
    const int sl   = threadIdx.x & 15;
    if (node >= kN) return;
    int c = cnt[node];
    if (c > kCAP) c = kCAP;
    int2* al = adj + (size_t)node * kCAP;
    const int2 e0 = al[sl];
    const int2 e1 = al[sl + 16];
    float s0 = 0.f, s1 = 0.f;
    if (sl < c)      { const float2 m = maps2[e0.x]; s0 += m.x * m.x; s1 += m.y * m.y; }
    if (sl + 16 < c) { const float2 m = maps2[e1.x]; s0 += m.x * m.x; s1 += m.y * m.y; }
    const int cpad = (c + 7) & ~7;
    if (sl >= c && sl < cpad)           al[sl]      = make_int2(kE2, node);
    if (sl + 16 >= c && sl + 16 < cpad) al[sl + 16] = make_int2(kE2, node);
    #pragma unroll
    for (int o = 8; o > 0; o >>= 1) {
        s0 += __shfl_xor(s0, o);
        s1 += __shfl_xor(s1, o);
    }
    if (sl == 0) diag[node] = make_float2(s0, s1);
}

// ---------------------------------------------------------------------------
// k_off: per ORIGINAL edge j: off[j] = -m_fwd*m_bwd * rsqrt((ds+1)(dt+1))
// Thread kE0 also writes the sentinel zero entry off[kE0].
// ---------------------------------------------------------------------------
__global__ __launch_bounds__(256) void k_off(
    const int* __restrict__ src, const int* __restrict__ dst,
    const float2* __restrict__ maps2, const float2* __restrict__ diag,
    float2* __restrict__ off)
{
    const int j = blockIdx.x * 256 + threadIdx.x;
    if (j >= kE0) {
        if (j == kE0) off[kE0] = make_float2(0.f, 0.f);
        return;
    }
    const float2 ma = maps2[j];
    const float2 mb = maps2[j + kE0];
    const int s = src[j], d = dst[j];
    const float2 ds = diag[s], dt = diag[d];
    off[j] = make_float2(-ma.x * mb.x * rsqrtf((ds.x + 1.0f) * (dt.x + 1.0f)),
                         -ma.y * mb.y * rsqrtf((ds.y + 1.0f) * (dt.y + 1.0f)));
}

// ---------------------------------------------------------------------------
// k_gather: one wave per node; lane covers (d = lane>>5, h4 = (lane&31)*4)
// 8-wide mask-free MLP loop (pad to mult of 8 — r15: time scales with
// padded slot count; 8 is the sweet spot). ALL NAMED SCALARS (no private
// arrays -> no LDS promotion). Packed-f16 accumulation; f32 merge.
// ---------------------------------------------------------------------------
__global__ __launch_bounds__(256) void k_gather(
    const f16* __restrict__ xb, const float* __restrict__ diag,
    const float2* __restrict__ off, const int* __restrict__ cnt,
    const int2* __restrict__ adj, float* __restrict__ y)
{
    const int node = blockIdx.x * 4 + (threadIdx.x >> 6);
    const int lane = threadIdx.x & 63;
    const int d    = lane >> 5;
    const int h4   = (lane & 31) << 2;
    const size_t rowoff = ((size_t)node * 2 + d) * 128 + h4;
    const f16x4 own = *(const f16x4*)(xb + rowoff);
    const float dv  = diag[node * 2 + d];
    const float dg  = dv / (dv + 1.0f);             // dis*diag*dis exactly
    f32x4 acc = {dg * (float)own[0], dg * (float)own[1],
                 dg * (float)own[2], dg * (float)own[3]};
    int c = cnt[node];
    if (c > kCAP) c = kCAP;
    const int2* al = adj + (size_t)node * kCAP;

    f16x4 acch = {(f16)0.f, (f16)0.f, (f16)0.f, (f16)0.f};
    for (int k = 0; k < c; k += 8) {
        const int4 ea = *(const int4*)(al + k);
        const int4 eb = *(const int4*)(al + k + 2);
        const int4 ec = *(const int4*)(al + k + 4);
        const int4 ed = *(const int4*)(al + k + 6);
        const int j0 = ea.x, n0 = ea.y, j1 = ea.z, n1 = ea.w;
        const int j2 = eb.x, n2 = eb.y, j3 = eb.z, n3 = eb.w;
        const int j4 = ec.x, n4 = ec.y, j5 = ec.z, n5 = ec.w;
        const int j6 = ed.x, n6 = ed.y, j7 = ed.z, n7 = ed.w;
        const float2 q0 = off[j0 - (j0 >= kE0 ? kE0 : 0)];
        const float2 q1 = off[j1 - (j1 >= kE0 ? kE0 : 0)];
        const float2 q2 = off[j2 - (j2 >= kE0 ? kE0 : 0)];
        const float2 q3 = off[j3 - (j3 >= kE0 ? kE0 : 0)];
        const float2 q4 = off[j4 - (j4 >= kE0 ? kE0 : 0)];
        const float2 q5 = off[j5 - (j5 >= kE0 ? kE0 : 0)];
        const float2 q6 = off[j6 - (j6 >= kE0 ? kE0 : 0)];
        const float2 q7 = off[j7 - (j7 >= kE0 ? kE0 : 0)];
        const f16x4 w0 = *(const f16x4*)(xb + ((size_t)n0 * 2 + d) * 128 + h4);
        const f16x4 w1 = *(const f16x4*)(xb + ((size_t)n1 * 2 + d) * 128 + h4);
        const f16x4 w2 = *(const f16x4*)(xb + ((size_t)n2 * 2 + d) * 128 + h4);
        const f16x4 w3 = *(const f16x4*)(xb + ((size_t)n3 * 2 + d) * 128 + h4);
        const f16x4 w4 = *(const f16x4*)(xb + ((size_t)n4 * 2 + d) * 128 + h4);
        const f16x4 w5 = *(const f16x4*)(xb + ((size_t)n5 * 2 + d) * 128 + h4);
        const f16x4 w6 = *(const f16x4*)(xb + ((size_t)n6 * 2 + d) * 128 + h4);
        const f16x4 w7 = *(const f16x4*)(xb + ((size_t)n7 * 2 + d) * 128 + h4);
        const f16 o0 = (f16)(d ? q0.y : q0.x);
        const f16 o1 = (f16)(d ? q1.y : q1.x);
        const f16 o2 = (f16)(d ? q2.y : q2.x);
        const f16 o3 = (f16)(d ? q3.y : q3.x);
        const f16 o4 = (f16)(d ? q4.y : q4.x);
        const f16 o5 = (f16)(d ? q5.y : q5.x);
        const f16 o6 = (f16)(d ? q6.y : q6.x);
        const f16 o7 = (f16)(d ? q7.y : q7.x);
        const f16x4 o40 = {o0, o0, o0, o0};
        const f16x4 o41 = {o1, o1, o1, o1};
        const f16x4 o42 = {o2, o2, o2, o2};
        const f16x4 o43 = {o3, o3, o3, o3};
        const f16x4 o44 = {o4, o4, o4, o4};
        const f16x4 o45 = {o5, o5, o5, o5};
        const f16x4 o46 = {o6, o6, o6, o6};
        const f16x4 o47 = {o7, o7, o7, o7};
        acch += o40 * w0;   // v_pk_fma_f16 pairs
        acch += o41 * w1;
        acch += o42 * w2;
        acch += o43 * w3;
        acch += o44 * w4;
        acch += o45 * w5;
        acch += o46 * w6;
        acch += o47 * w7;
    }
    acc[0] += (float)acch[0];
    acc[1] += (float)acch[1];
    acc[2] += (float)acch[2];
    acc[3] += (float)acch[3];
    __builtin_nontemporal_store(acc, (f32x4*)(y + rowoff));
}

// ---------------------------------------------------------------------------
extern "C" void kernel_launch(void* const* d_in, const int* in_sizes, int n_in,
                              void* d_out, int out_size, void* d_ws, size_t ws_size,
                              hipStream_t stream)
{
    const float* x   = (const float*)d_in[1];
    const int*   src = (const int*)d_in[2];
    const int*   dst = (const int*)d_in[3];
    const float* Wsh = (const float*)d_in[4];
    const float* Wl  = (const float*)d_in[5];
    const float* Wr  = (const float*)d_in[6];

    char* ws = (char*)d_ws;
    f16*    xb    = (f16*)   (ws + 0);           // 25,600,000 B
    float4* ab    = (float4*)(ws + 25600000);    //    800,000 B
    float2* maps2 = (float2*)(ws + 26400000);    //  3,200,000 B (2*E0 float2)
    float2* off   = (float2*)(ws + 29600000);    //  1,600,008 B (kE0+1 entries)
    float2* diag  = (float2*)(ws + 31200016);    //    400,000 B
    int*    cnt   = (int*)   (ws + 31600016);    //    200,000 B
    int2*   adj   = (int2*)  (ws + 31800016);    // 12,800,000 B (kCAP=32)

    k_node  <<<1563,  256, 0, stream>>>(x, Wsh, Wl, Wr, xb, (float*)ab, cnt);
    k_edge1 <<<782,   256, 0, stream>>>(src, dst, ab, maps2, cnt, adj);
    k_diag  <<<3125,  256, 0, stream>>>(cnt, adj, maps2, diag);
    k_off   <<<783,   256, 0, stream>>>(src, dst, maps2, diag, off);
    k_gather<<<12500, 256, 0, stream>>>(xb, (const float*)diag, off, cnt, adj, (float*)d_out);
}

// Round 18
// 108.437 us; speedup vs baseline: 1.3223x; 1.0613x over previous
//
#include <hip/hip_runtime.h>

static constexpr int kN     = 50000;    // nodes
static constexpr int kNR    = 100000;   // N*D rows
static constexpr int kE0    = 200000;   // original edges
static constexpr int kE2    = 400000;   // directed edges
static constexpr int kCAP   = 32;       // adjacency capacity per node
static constexpr int kTiles = 1563;     // 64-row node tiles

typedef _Float16 f16;
typedef f16   f16x8 __attribute__((ext_vector_type(8)));
typedef f16   f16x4 __attribute__((ext_vector_type(4)));
typedef float f32x4 __attribute__((ext_vector_type(4)));

// ---------------------------------------------------------------------------
// k_node (grid-stride): 768 blocks (3/CU), each stages W_right->Bl ONCE,
// then loops over ~2 node-tiles: {sync, stage Al, sync, ab-MFMA, GEMM}.
// Pass-1 B-fragments (Wsh) and blend coeffs hoisted into registers.
// ---------------------------------------------------------------------------
__global__ __launch_bounds__(256) void k_node(
    const float* __restrict__ x, const float* __restrict__ Wsh,
    const float* __restrict__ Wl, const float* __restrict__ Wr,
    f16* __restrict__ xb, float* __restrict__ abf, int* __restrict__ cnt)
{
    __shared__ f16 Al[64][136];     // raw x rows (+8 pad)      17.4 KB
    __shared__ f16 Bl[128][136];    // W_right rows (+8 pad)    34.8 KB

    const int t = threadIdx.x;
    const int w = t >> 6, lane = t & 63;
    const int lr = lane & 15, lk = lane >> 4;

    // zero cnt (768*256 = 196608 threads >= kN)
    const int gid = blockIdx.x * 256 + t;
    if (gid < kN) cnt[gid] = 0;

    // stage Wr f32 -> Bl f16 ONCE per block
    #pragma unroll
    for (int i = 0; i < 8; ++i) {
        const int idx = i * 256 + t;
        const int row = idx >> 4;            // 0..127
        const int c8  = (idx & 15) << 3;     // 0..120
        const float4 a = *(const float4*)(Wr + row * 128 + c8);
        const float4 b = *(const float4*)(Wr + row * 128 + c8 + 4);
        f16x8 tv;
        tv[0] = (f16)a.x; tv[1] = (f16)a.y; tv[2] = (f16)a.z; tv[3] = (f16)a.w;
        tv[4] = (f16)b.x; tv[5] = (f16)b.y; tv[6] = (f16)b.z; tv[7] = (f16)b.w;
        *(f16x8*)&Bl[row][c8] = tv;
    }

    // hoist pass-1 B fragments: row j=lr of the 8-vector Wsh table (lr<8)
    f16x8 bw0 = {}, bw1 = {}, bw2 = {}, bw3 = {};
    if (lr < 8) {
        const int srcoff = ((lr >> 2) ? 256 : 0) + (((lr >> 1) & 1) ? 512 : 0) + ((lr & 1) ? 128 : 0);
        #pragma unroll
        for (int kk = 0; kk < 4; ++kk) {
            const float4 a = *(const float4*)(Wsh + srcoff + kk * 32 + lk * 8);
            const float4 b = *(const float4*)(Wsh + srcoff + kk * 32 + lk * 8 + 4);
            f16x8 bv;
            bv[0] = (f16)a.x; bv[1] = (f16)a.y; bv[2] = (f16)a.z; bv[3] = (f16)a.w;
            bv[4] = (f16)b.x; bv[5] = (f16)b.y; bv[6] = (f16)b.z; bv[7] = (f16)b.w;
            if (kk == 0) bw0 = bv; else if (kk == 1) bw1 = bv;
            else if (kk == 2) bw2 = bv; else bw3 = bv;
        }
    }

    // hoist blend coeffs
    const float wl00 = Wl[0], wl01 = Wl[1], wl10 = Wl[2], wl11 = Wl[3];
    const int dp = lr & 1;
    const f16 cS = (f16)(dp ? wl11 : wl00);   // coeff on x[r]
    const f16 cP = (f16)(dp ? wl10 : wl01);   // coeff on x[r^1]
    const f16x8 cS8 = {cS, cS, cS, cS, cS, cS, cS, cS};
    const f16x8 cP8 = {cP, cP, cP, cP, cP, cP, cP, cP};

    for (int tile = blockIdx.x; tile < kTiles; tile += gridDim.x) {
        __syncthreads();   // prev-tile Al reads done (and tile0: Bl+Al write order)

        // stage raw x -> Al (b128 writes)
        #pragma unroll
        for (int i = 0; i < 4; ++i) {
            const int f8   = i * 256 + t;
            const int row  = f8 >> 4;            // 0..63
            const int c8   = (f8 & 15) << 3;     // 0..120
            const int grow = tile * 64 + row;
            float4 xa = make_float4(0.f, 0.f, 0.f, 0.f), xc = xa;
            if (grow < kNR) {
                xa = *(const float4*)(x + (size_t)grow * 128 + c8);
                xc = *(const float4*)(x + (size_t)grow * 128 + c8 + 4);
            }
            f16x8 tv;
            tv[0] = (f16)xa.x; tv[1] = (f16)xa.y; tv[2] = (f16)xa.z; tv[3] = (f16)xa.w;
            tv[4] = (f16)xc.x; tv[5] = (f16)xc.y; tv[6] = (f16)xc.z; tv[7] = (f16)xc.w;
            *(f16x8*)&Al[row][c8] = tv;
        }
        __syncthreads();

        // load x fragments: own row r = 16w+lr and partner row r^1
        f16x8 xfr[4], xpr[4];
        #pragma unroll
        for (int kk = 0; kk < 4; ++kk) {
            xfr[kk] = *(const f16x8*)&Al[16 * w + lr][kk * 32 + lk * 8];
            xpr[kk] = *(const f16x8*)&Al[16 * w + (lr ^ 1)][kk * 32 + lk * 8];
        }

        // ---- pass 1: ab via MFMA (cols 8..15 zero) ----
        f32x4 cab = {0.f, 0.f, 0.f, 0.f};
        cab = __builtin_amdgcn_mfma_f32_16x16x32_f16(xfr[0], bw0, cab, 0, 0, 0);
        cab = __builtin_amdgcn_mfma_f32_16x16x32_f16(xfr[1], bw1, cab, 0, 0, 0);
        cab = __builtin_amdgcn_mfma_f32_16x16x32_f16(xfr[2], bw2, cab, 0, 0, 0);
        cab = __builtin_amdgcn_mfma_f32_16x16x32_f16(xfr[3], bw3, cab, 0, 0, 0);
        #pragma unroll
        for (int tt = 0; tt < 2; ++tt) {
            const float hi_reg  = cab[2 * tt + 1];
            const float partner = __shfl_xor(hi_reg, 1);   // C[2n+1][lr^1]
            const float val     = cab[2 * tt] + partner;   // valid on even lr
            if (!(lr & 1) && lr < 8) {
                const int node = tile * 32 + 8 * w + 2 * lk + tt;
                if (node < kN) abf[node * 4 + (lr >> 1)] = val;
            }
        }

        // ---- pass 2: blend tmp fragments + main GEMM from Bl ----
        f16x8 tfr[4];
        #pragma unroll
        for (int kk = 0; kk < 4; ++kk)
            tfr[kk] = cS8 * xfr[kk] + cP8 * xpr[kk];

        const int grow = tile * 64 + 16 * w + lr;   // node-row this lane outputs
        #pragma unroll
        for (int j = 0; j < 8; ++j) {
            f32x4 acc = {0.f, 0.f, 0.f, 0.f};
            #pragma unroll
            for (int kk = 0; kk < 4; ++kk) {
                const f16x8 wfr = *(const f16x8*)&Bl[j * 16 + lr][kk * 32 + lk * 8];
                acc = __builtin_amdgcn_mfma_f32_16x16x32_f16(wfr, tfr[kk], acc, 0, 0, 0);
            }
            f16x4 ov;
            ov[0] = (f16)(-acc[0]); ov[1] = (f16)(-acc[1]);
            ov[2] = (f16)(-acc[2]); ov[3] = (f16)(-acc[3]);
            if (grow < kNR)
                *(f16x4*)(xb + (size_t)grow * 128 + j * 16 + lk * 4) = ov;
        }
    }
}

// ---------------------------------------------------------------------------
// k_edge1: per ORIGINAL edge j (200K threads): both directions share the
// same two ab float4s. maps2[j]=fwd, maps2[j+kE0]=bwd; 2 atomics/edge.
// ---------------------------------------------------------------------------
__global__ __launch_bounds__(256) void k_edge1(
    const int* __restrict__ src, const int* __restrict__ dst,
    const float4* __restrict__ ab, float2* __restrict__ maps2,
    int* __restrict__ cnt, int2* __restrict__ adj)
{
    const int j = blockIdx.x * 256 + threadIdx.x;
    if (j >= kE0) return;
    const int s = src[j], d = dst[j];
    const float4 as_ = ab[s], ad = ab[d];
    const float f0 = tanhf(as_.x + ad.z);
    const float f1 = tanhf(as_.y + ad.w);
    const float b0 = tanhf(ad.x + as_.z);
    const float b1 = tanhf(ad.y + as_.w);
    maps2[j]       = make_float2(f0, f1);
    maps2[j + kE0] = make_float2(b0, b1);
    const int p = atomicAdd(&cnt[s], 1);
    if (p < kCAP) adj[(size_t)s * kCAP + p] = make_int2(j, d);
    const int q = atomicAdd(&cnt[d], 1);
    if (q < kCAP) adj[(size_t)d * kCAP + q] = make_int2(j + kE0, s);
}

// ---------------------------------------------------------------------------
// k_diag: 16 lanes per node. Parallel slot gathers (slots sl, sl+16),
// 4-step shfl reduce; sentinel-pads adjacency to multiple of 8.
// ---------------------------------------------------------------------------
__global__ __launch_bounds__(256) void k_diag(
    const int* __restrict__ cnt, int2* __restrict__ adj,
    const float2* __restrict__ maps2, float2* __restrict__ diag)
{
    const int node = blockIdx.x * 16 + (threadIdx.x >> 4);
    const int sl   = threadIdx.x & 15;
    if (node >= kN) return;
    int c = cnt[node];
    if (c > kCAP) c = kCAP;
    int2* al = adj + (size_t)node * kCAP;
    const int2 e0 = al[sl];
    const int2 e1 = al[sl + 16];
    float s0 = 0.f, s1 = 0.f;
    if (sl < c)      { const float2 m = maps2[e0.x]; s0 += m.x * m.x; s1 += m.y * m.y; }
    if (sl + 16 < c) { const float2 m = maps2[e1.x]; s0 += m.x * m.x; s1 += m.y * m.y; }
    const int cpad = (c + 7) & ~7;
    if (sl >= c && sl < cpad)           al[sl]      = make_int2(kE2, node);
    if (sl + 16 >= c && sl + 16 < cpad) al[sl + 16] = make_int2(kE2, node);
    #pragma unroll
    for (int o = 8; o > 0; o >>= 1) {
        s0 += __shfl_xor(s0, o);
        s1 += __shfl_xor(s1, o);
    }
    if (sl == 0) diag[node] = make_float2(s0, s1);
}

// ---------------------------------------------------------------------------
// k_off: per ORIGINAL edge j: off[j] = -m_fwd*m_bwd * rsqrt((ds+1)(dt+1))
// Thread kE0 also writes the sentinel zero entry off[kE0].
// ---------------------------------------------------------------------------
__global__ __launch_bounds__(256) void k_off(
    const int* __restrict__ src, const int* __restrict__ dst,
    const float2* __restrict__ maps2, const float2* __restrict__ diag,
    float2* __restrict__ off)
{
    const int j = blockIdx.x * 256 + threadIdx.x;
    if (j >= kE0) {
        if (j == kE0) off[kE0] = make_float2(0.f, 0.f);
        return;
    }
    const float2 ma = maps2[j];
    const float2 mb = maps2[j + kE0];
    const int s = src[j], d = dst[j];
    const float2 ds = diag[s], dt = diag[d];
    off[j] = make_float2(-ma.x * mb.x * rsqrtf((ds.x + 1.0f) * (dt.x + 1.0f)),
                         -ma.y * mb.y * rsqrtf((ds.y + 1.0f) * (dt.y + 1.0f)));
}

// ---------------------------------------------------------------------------
// k_gather: one wave per node; lane covers (d = lane>>5, h4 = (lane&31)*4)
// 8-wide mask-free MLP loop (pad to mult of 8). ALL NAMED SCALARS.
// Packed-f16 accumulation; f32 merge. At L3-random-line throughput floor
// (r13-r17: ~51us across 5 structural variants; scales with slot count).
// ---------------------------------------------------------------------------
__global__ __launch_bounds__(256) void k_gather(
    const f16* __restrict__ xb, const float* __restrict__ diag,
    const float2* __restrict__ off, const int* __restrict__ cnt,
    const int2* __restrict__ adj, float* __restrict__ y)
{
    const int node = blockIdx.x * 4 + (threadIdx.x >> 6);
    const int lane = threadIdx.x & 63;
    const int d    = lane >> 5;
    const int h4   = (lane & 31) << 2;
    const size_t rowoff = ((size_t)node * 2 + d) * 128 + h4;
    const f16x4 own = *(const f16x4*)(xb + rowoff);
    const float dv  = diag[node * 2 + d];
    const float dg  = dv / (dv + 1.0f);             // dis*diag*dis exactly
    f32x4 acc = {dg * (float)own[0], dg * (float)own[1],
                 dg * (float)own[2], dg * (float)own[3]};
    int c = cnt[node];
    if (c > kCAP) c = kCAP;
    const int2* al = adj + (size_t)node * kCAP;

    f16x4 acch = {(f16)0.f, (f16)0.f, (f16)0.f, (f16)0.f};
    for (int k = 0; k < c; k += 8) {
        const int4 ea = *(const int4*)(al + k);
        const int4 eb = *(const int4*)(al + k + 2);
        const int4 ec = *(const int4*)(al + k + 4);
        const int4 ed = *(const int4*)(al + k + 6);
        const int j0 = ea.x, n0 = ea.y, j1 = ea.z, n1 = ea.w;
        const int j2 = eb.x, n2 = eb.y, j3 = eb.z, n3 = eb.w;
        const int j4 = ec.x, n4 = ec.y, j5 = ec.z, n5 = ec.w;
        const int j6 = ed.x, n6 = ed.y, j7 = ed.z, n7 = ed.w;
        const float2 q0 = off[j0 - (j0 >= kE0 ? kE0 : 0)];
        const float2 q1 = off[j1 - (j1 >= kE0 ? kE0 : 0)];
        const float2 q2 = off[j2 - (j2 >= kE0 ? kE0 : 0)];
        const float2 q3 = off[j3 - (j3 >= kE0 ? kE0 : 0)];
        const float2 q4 = off[j4 - (j4 >= kE0 ? kE0 : 0)];
        const float2 q5 = off[j5 - (j5 >= kE0 ? kE0 : 0)];
        const float2 q6 = off[j6 - (j6 >= kE0 ? kE0 : 0)];
        const float2 q7 = off[j7 - (j7 >= kE0 ? kE0 : 0)];
        const f16x4 w0 = *(const f16x4*)(xb + ((size_t)n0 * 2 + d) * 128 + h4);
        const f16x4 w1 = *(const f16x4*)(xb + ((size_t)n1 * 2 + d) * 128 + h4);
        const f16x4 w2 = *(const f16x4*)(xb + ((size_t)n2 * 2 + d) * 128 + h4);
        const f16x4 w3 = *(const f16x4*)(xb + ((size_t)n3 * 2 + d) * 128 + h4);
        const f16x4 w4 = *(const f16x4*)(xb + ((size_t)n4 * 2 + d) * 128 + h4);
        const f16x4 w5 = *(const f16x4*)(xb + ((size_t)n5 * 2 + d) * 128 + h4);
        const f16x4 w6 = *(const f16x4*)(xb + ((size_t)n6 * 2 + d) * 128 + h4);
        const f16x4 w7 = *(const f16x4*)(xb + ((size_t)n7 * 2 + d) * 128 + h4);
        const f16 o0 = (f16)(d ? q0.y : q0.x);
        const f16 o1 = (f16)(d ? q1.y : q1.x);
        const f16 o2 = (f16)(d ? q2.y : q2.x);
        const f16 o3 = (f16)(d ? q3.y : q3.x);
        const f16 o4 = (f16)(d ? q4.y : q4.x);
        const f16 o5 = (f16)(d ? q5.y : q5.x);
        const f16 o6 = (f16)(d ? q6.y : q6.x);
        const f16 o7 = (f16)(d ? q7.y : q7.x);
        const f16x4 o40 = {o0, o0, o0, o0};
        const f16x4 o41 = {o1, o1, o1, o1};
        const f16x4 o42 = {o2, o2, o2, o2};
        const f16x4 o43 = {o3, o3, o3, o3};
        const f16x4 o44 = {o4, o4, o4, o4};
        const f16x4 o45 = {o5, o5, o5, o5};
        const f16x4 o46 = {o6, o6, o6, o6};
        const f16x4 o47 = {o7, o7, o7, o7};
        acch += o40 * w0;   // v_pk_fma_f16 pairs
        acch += o41 * w1;
        acch += o42 * w2;
        acch += o43 * w3;
        acch += o44 * w4;
        acch += o45 * w5;
        acch += o46 * w6;
        acch += o47 * w7;
    }
    acc[0] += (float)acch[0];
    acc[1] += (float)acch[1];
    acc[2] += (float)acch[2];
    acc[3] += (float)acch[3];
    __builtin_nontemporal_store(acc, (f32x4*)(y + rowoff));
}

// ---------------------------------------------------------------------------
extern "C" void kernel_launch(void* const* d_in, const int* in_sizes, int n_in,
                              void* d_out, int out_size, void* d_ws, size_t ws_size,
                              hipStream_t stream)
{
    const float* x   = (const float*)d_in[1];
    const int*   src = (const int*)d_in[2];
    const int*   dst = (const int*)d_in[3];
    const float* Wsh = (const float*)d_in[4];
    const float* Wl  = (const float*)d_in[5];
    const float* Wr  = (const float*)d_in[6];

    char* ws = (char*)d_ws;
    f16*    xb    = (f16*)   (ws + 0);           // 25,600,000 B
    float4* ab    = (float4*)(ws + 25600000);    //    800,000 B
    float2* maps2 = (float2*)(ws + 26400000);    //  3,200,000 B (2*E0 float2)
    float2* off   = (float2*)(ws + 29600000);    //  1,600,008 B (kE0+1 entries)
    float2* diag  = (float2*)(ws + 31200016);    //    400,000 B
    int*    cnt   = (int*)   (ws + 31600016);    //    200,000 B
    int2*   adj   = (int2*)  (ws + 31800016);    // 12,800,000 B (kCAP=32)

    k_node  <<<768,   256, 0, stream>>>(x, Wsh, Wl, Wr, xb, (float*)ab, cnt);
    k_edge1 <<<782,   256, 0, stream>>>(src, dst, ab, maps2, cnt, adj);
    k_diag  <<<3125,  256, 0, stream>>>(cnt, adj, maps2, diag);
    k_off   <<<783,   256, 0, stream>>>(src, dst, maps2, diag, off);
    k_gather<<<12500, 256, 0, stream>>>(xb, (const float*)diag, off, cnt, adj, (float*)d_out);
}